// Round 4
// baseline (231.960 us; speedup 1.0000x reference)
//
#include <hip/hip_runtime.h>

typedef unsigned int uint;
typedef unsigned short ushort;

#define IN_C 128
#define HID  32

// ---- f16 helpers (fp32 accumulate everywhere; RNE on store) ---------------
__device__ __forceinline__ uint f2h2(float a, float b) {
    _Float16 ha = (_Float16)a, hb = (_Float16)b;
    unsigned short ua = __builtin_bit_cast(unsigned short, ha);
    unsigned short ub = __builtin_bit_cast(unsigned short, hb);
    return (uint)ua | ((uint)ub << 16);
}
// acc += f16_lo(pk) * v  -- single full-rate VOP3P v_fma_mix_f32, no unpack
__device__ __forceinline__ void fma_lo(float& acc, uint pk, float v) {
    asm("v_fma_mix_f32 %0, %1, %2, %0 op_sel:[0,0,0] op_sel_hi:[1,0,0]"
        : "+v"(acc) : "v"(pk), "v"(v));
}
// acc += f16_hi(pk) * v
__device__ __forceinline__ void fma_hi(float& acc, uint pk, float v) {
    asm("v_fma_mix_f32 %0, %1, %2, %0 op_sel:[1,0,0] op_sel_hi:[1,0,0]"
        : "+v"(acc) : "v"(pk), "v"(v));
}

// ---------------------------------------------------------------------------
// K1: fused prep (unchanged).
// ---------------------------------------------------------------------------
__global__ void prep_kernel(const float* __restrict__ x,
                            const float* __restrict__ w,
                            ushort* __restrict__ r0,
                            const int* __restrict__ a1r, int E1, int* __restrict__ ip1,
                            const int* __restrict__ a2r, int E2, int* __restrict__ ip2,
                            const int* __restrict__ a2c, const float* __restrict__ a2v,
                            float* __restrict__ dummy,
                            int n, int nbE, int nbI, int nbT) {
    __shared__ float wl[IN_C * HID];
    const int tid = threadIdx.x;
    if (blockIdx.x < nbE) {
        for (int i = tid; i < IN_C * HID; i += blockDim.x) wl[i] = w[i];
        __syncthreads();
        const int row = blockIdx.x * 16 + tid / 16;
        const int h0  = (tid % 16) * 2;
        if (row >= n) return;
        const float4* xr = (const float4*)(x + (size_t)row * IN_C);
        float a0 = 0.f, a1 = 0.f;
#pragma unroll
        for (int k4 = 0; k4 < IN_C / 4; ++k4) {
            float4 xv = xr[k4];
            a0 += xv.x * wl[(4*k4+0)*HID + h0];  a1 += xv.x * wl[(4*k4+0)*HID + h0+1];
            a0 += xv.y * wl[(4*k4+1)*HID + h0];  a1 += xv.y * wl[(4*k4+1)*HID + h0+1];
            a0 += xv.z * wl[(4*k4+2)*HID + h0];  a1 += xv.z * wl[(4*k4+2)*HID + h0+1];
            a0 += xv.w * wl[(4*k4+3)*HID + h0];  a1 += xv.w * wl[(4*k4+3)*HID + h0+1];
        }
        uint p = f2h2(fmaxf(a0, 0.f), fmaxf(a1, 0.f));
        ((uint*)r0)[(size_t)row * 16 + (tid % 16)] = p;
    } else if (blockIdx.x < nbE + nbI) {
        const int i = (blockIdx.x - nbE) * 256 + tid;
        if (i > n) return;
        int lo = 0, hi = E1;
        while (lo < hi) { int m = (lo + hi) >> 1; if (a1r[m] < i) lo = m + 1; else hi = m; }
        ip1[i] = lo;
        lo = 0; hi = E2;
        while (lo < hi) { int m = (lo + hi) >> 1; if (a2r[m] < i) lo = m + 1; else hi = m; }
        ip2[i] = lo;
    } else {
        const int t = (blockIdx.x - nbE - nbI) * 256 + tid;
        const int stride = nbT * 256;
        const int total4 = E2 / 4;
        const float4* c4 = (const float4*)a2c;
        const float4* v4 = (const float4*)a2v;
        float s = 0.f;
        for (int i = t; i < total4; i += stride) {
            float4 u = c4[i], v = v4[i];
            s += u.x + u.y + u.z + u.w + v.x + v.y + v.z + v.w;
        }
        if (s == 123.456f) dummy[0] = s;   // never true in practice; defeats DCE
    }
}

// ---------------------------------------------------------------------------
// K2: fused-level SpMM + ReLU, f16 features / fp32 accumulate (v_fma_mix).
// R4: dual-row pairing on the heavy (A2) path. Each subgroup owns TWO
// consecutive rows; per iteration: issue gathers A, gathers B, prefetch next
// edge batches (consumed ACROSS the loop backedge -> collapse-proof), then
// fma A (covers B's gather latency), fma B. Independent A/B chains double
// per-wave memory-level parallelism without sched_barrier games (R3 lesson:
// pins regress; structure must be collapse-proof by construction).
// Degree mismatch: clamped batch offsets + val-zeroing for the shorter row.
// Light (A1) path = R2 version (depth-1 pipelined per-edge loop).
// Blocks [0,nbH) = A2 pairs (out col off C); rest = A1 (off 0).
// ---------------------------------------------------------------------------
template <int C, int ROWS>
__global__ __launch_bounds__(256) void spmm_level(
        const int* __restrict__ ip1, const int* __restrict__ col1,
        const float* __restrict__ val1, int E1,
        const int* __restrict__ ip2, const int* __restrict__ col2,
        const float* __restrict__ val2, int E2,
        const ushort* __restrict__ xin, ushort* __restrict__ out,
        int n, int nbH) {
    constexpr int L    = C / 8;        // feature lanes per row
    constexpr int SUBL = 64 / ROWS;    // lanes per row-group
    constexpr int W    = SUBL / L;     // edge ways per row
    const int lane = threadIdx.x & 63;
    const int wave = threadIdx.x >> 6;
    const int sub  = lane / SUBL;
    const int li   = lane % SUBL;
    const int fl   = li % L;
    const int way  = li / L;

    const uint flo = (uint)fl * 16u;   // byte offset of this lane's 8 feats
    auto gat = [&](uint c) -> uint4 {
        return *(const uint4*)((const char*)xin + (c * (uint)(2 * C) + flo));
    };
    auto fmadd = [&](float (&ac)[8], const uint4& u, float v) {
        fma_lo(ac[0], u.x, v); fma_hi(ac[1], u.x, v);
        fma_lo(ac[2], u.y, v); fma_hi(ac[3], u.y, v);
        fma_lo(ac[4], u.z, v); fma_hi(ac[5], u.z, v);
        fma_lo(ac[6], u.w, v); fma_hi(ac[7], u.w, v);
    };
    auto redstore = [&](float (&ac)[8], int row, int off) {
#pragma unroll
        for (int m = L; m < SUBL; m <<= 1)
#pragma unroll
            for (int j = 0; j < 8; ++j) ac[j] += __shfl_xor(ac[j], m, 64);
        if (way == 0 && row < n) {
            uint4 p;
            p.x = f2h2(fmaxf(ac[0], 0.f), fmaxf(ac[1], 0.f));
            p.y = f2h2(fmaxf(ac[2], 0.f), fmaxf(ac[3], 0.f));
            p.z = f2h2(fmaxf(ac[4], 0.f), fmaxf(ac[5], 0.f));
            p.w = f2h2(fmaxf(ac[6], 0.f), fmaxf(ac[7], 0.f));
            *(uint4*)(out + (size_t)row * (2 * C) + off + fl * 8) = p;
        }
    };

    int bid = blockIdx.x;
    if (bid < nbH) {
        // ---------------- heavy path: A2, two consecutive rows -------------
        const int gid  = (bid * 4 + wave) * ROWS + sub;
        const int rowA = gid * 2;
        const int rowB = rowA + 1;
        if (rowA >= n) return;
        const int* __restrict__ col = col2;
        const float* __restrict__ val = val2;
        const int emaxAl = (E2 - 4) & ~3;

        const int sA = ip2[rowA];
        const int eA = ip2[rowA + 1];
        int sB = eA, eB = eA;
        if (rowB < n) eB = ip2[rowB + 1];   // sB == eA (consecutive rows)

        float accA[8], accB[8];
#pragma unroll
        for (int j = 0; j < 8; ++j) { accA[j] = 0.f; accB[j] = 0.f; }

        // heads (unaligned, <=3 edges each)
        int svA = (sA + 3) & ~3; if (svA > eA) svA = eA;
        int svB = (sB + 3) & ~3; if (svB > eB) svB = eB;
        for (int idx = sA + way; idx < svA; idx += W) fmadd(accA, gat((uint)col[idx]), val[idx]);
        for (int idx = sB + way; idx < svB; idx += W) fmadd(accB, gat((uint)col[idx]), val[idx]);

        const int nvA = (eA - svA) / (4 * W);
        const int nvB = (eB - svB) / (4 * W);
        const int nvM = (nvA > nvB) ? nvA : nvB;

        if (nvM > 0) {
            auto boff = [&](int i, int nv, int sv) -> int {
                int ii = (i < nv) ? i : (nv > 0 ? nv - 1 : 0);
                int a = sv + (ii * W + way) * 4;
                return (a < emaxAl) ? a : emaxAl;     // aligned, in-bounds
            };
            // prologue: edge batches 0 for both rows
            int oA = boff(0, nvA, svA), oB = boff(0, nvB, svB);
            int4   cA = *(const int4*)  (col + oA);
            float4 vA = *(const float4*)(val + oA);
            int4   cB = *(const int4*)  (col + oB);
            float4 vB = *(const float4*)(val + oB);
            for (int i = 0; i < nvM; ++i) {
                // gathers first (L2-fast stream retires independently of the
                // slower edge stream; VMEM retires in issue order)
                const uint4 a0 = gat((uint)cA.x), a1 = gat((uint)cA.y),
                            a2 = gat((uint)cA.z), a3 = gat((uint)cA.w);
                const uint4 b0 = gat((uint)cB.x), b1 = gat((uint)cB.y),
                            b2 = gat((uint)cB.z), b3 = gat((uint)cB.w);
                // edge prefetch for i+1; consumed across the backedge ->
                // the scheduler cannot collapse this distance
                int oA1 = boff(i + 1, nvA, svA), oB1 = boff(i + 1, nvB, svB);
                int4   cA1 = *(const int4*)  (col + oA1);
                float4 vA1 = *(const float4*)(val + oA1);
                int4   cB1 = *(const int4*)  (col + oB1);
                float4 vB1 = *(const float4*)(val + oB1);
                const bool la = (i < nvA), lb = (i < nvB);
                // fma A covers gather-B latency; only gather-A partially exposed
                fmadd(accA, a0, la ? vA.x : 0.f); fmadd(accA, a1, la ? vA.y : 0.f);
                fmadd(accA, a2, la ? vA.z : 0.f); fmadd(accA, a3, la ? vA.w : 0.f);
                fmadd(accB, b0, lb ? vB.x : 0.f); fmadd(accB, b1, lb ? vB.y : 0.f);
                fmadd(accB, b2, lb ? vB.z : 0.f); fmadd(accB, b3, lb ? vB.w : 0.f);
                cA = cA1; vA = vA1; cB = cB1; vB = vB1;
            }
        }
        // tails
        for (int idx = svA + nvA * 4 * W + way; idx < eA; idx += W)
            fmadd(accA, gat((uint)col[idx]), val[idx]);
        for (int idx = svB + nvB * 4 * W + way; idx < eB; idx += W)
            fmadd(accB, gat((uint)col[idx]), val[idx]);

        redstore(accA, rowA, C);
        redstore(accB, rowB, C);
    } else {
        // ---------------- light path: A1, one row (R2 structure) -----------
        bid -= nbH;
        const int row = (bid * 4 + wave) * ROWS + sub;
        if (row >= n) return;
        const int* __restrict__ col = col1;
        const float* __restrict__ val = val1;

        float acc[8];
#pragma unroll
        for (int j = 0; j < 8; ++j) acc[j] = 0.f;

        const int s = ip1[row];
        const int e = ip1[row + 1];
        int idx0 = s + way;
        if (idx0 < e) {
            int c0 = col[idx0]; float v0 = val[idx0];
            int idx1 = idx0 + W;
            int c1 = 0; float v1 = 0.f;
            if (idx1 < e) { c1 = col[idx1]; v1 = val[idx1]; }
            uint4 g0 = gat((uint)c0);
            while (true) {
                int idx2 = idx1 + W;
                int c2 = 0; float v2 = 0.f;
                if (idx2 < e) { c2 = col[idx2]; v2 = val[idx2]; }
                uint4 g1 = gat((uint)c1);
                fmadd(acc, g0, v0);
                if (idx1 >= e) break;
                g0 = g1; c1 = c2; v0 = v1; v1 = v2;
                idx1 = idx2;
            }
        }
        redstore(acc, row, 0);
    }
}

// ---------------------------------------------------------------------------
// K3: out = [r0 | r1 | r2] @ w_classify  (f16 features via v_fma_mix,
// fp32 weights in LDS)
// ---------------------------------------------------------------------------
#define CDIM 224
#define OUT_C 16
__global__ void classify_kernel(const ushort* __restrict__ r0,
                                const ushort* __restrict__ r1,
                                const ushort* __restrict__ r2,
                                const float* __restrict__ w,
                                float* __restrict__ out, int n) {
    __shared__ float wl[CDIM * OUT_C];
    const int tid = threadIdx.x;
    for (int i = tid; i < CDIM * OUT_C; i += blockDim.x) wl[i] = w[i];
    __syncthreads();
    const int row = blockIdx.x * 16 + tid / 16;
    const int o   = tid % 16;
    if (row >= n) return;
    float acc = 0.f;

    const uint4* a = (const uint4*)(r0 + (size_t)row * 32);
#pragma unroll
    for (int q = 0; q < 4; ++q) {
        uint4 u = a[q]; int j = q * 8;
        fma_lo(acc, u.x, wl[(j+0)*OUT_C + o]);  fma_hi(acc, u.x, wl[(j+1)*OUT_C + o]);
        fma_lo(acc, u.y, wl[(j+2)*OUT_C + o]);  fma_hi(acc, u.y, wl[(j+3)*OUT_C + o]);
        fma_lo(acc, u.z, wl[(j+4)*OUT_C + o]);  fma_hi(acc, u.z, wl[(j+5)*OUT_C + o]);
        fma_lo(acc, u.w, wl[(j+6)*OUT_C + o]);  fma_hi(acc, u.w, wl[(j+7)*OUT_C + o]);
    }
    const uint4* b = (const uint4*)(r1 + (size_t)row * 64);
#pragma unroll
    for (int q = 0; q < 8; ++q) {
        uint4 u = b[q]; int j = 32 + q * 8;
        fma_lo(acc, u.x, wl[(j+0)*OUT_C + o]);  fma_hi(acc, u.x, wl[(j+1)*OUT_C + o]);
        fma_lo(acc, u.y, wl[(j+2)*OUT_C + o]);  fma_hi(acc, u.y, wl[(j+3)*OUT_C + o]);
        fma_lo(acc, u.z, wl[(j+4)*OUT_C + o]);  fma_hi(acc, u.z, wl[(j+5)*OUT_C + o]);
        fma_lo(acc, u.w, wl[(j+6)*OUT_C + o]);  fma_hi(acc, u.w, wl[(j+7)*OUT_C + o]);
    }
    const uint4* c = (const uint4*)(r2 + (size_t)row * 128);
#pragma unroll
    for (int q = 0; q < 16; ++q) {
        uint4 u = c[q]; int j = 96 + q * 8;
        fma_lo(acc, u.x, wl[(j+0)*OUT_C + o]);  fma_hi(acc, u.x, wl[(j+1)*OUT_C + o]);
        fma_lo(acc, u.y, wl[(j+2)*OUT_C + o]);  fma_hi(acc, u.y, wl[(j+3)*OUT_C + o]);
        fma_lo(acc, u.z, wl[(j+4)*OUT_C + o]);  fma_hi(acc, u.z, wl[(j+5)*OUT_C + o]);
        fma_lo(acc, u.w, wl[(j+6)*OUT_C + o]);  fma_hi(acc, u.w, wl[(j+7)*OUT_C + o]);
    }
    out[(size_t)row * OUT_C + o] = acc;
}

// ---------------------------------------------------------------------------
extern "C" void kernel_launch(void* const* d_in, const int* in_sizes, int n_in,
                              void* d_out, int out_size, void* d_ws, size_t ws_size,
                              hipStream_t stream) {
    const float* x   = (const float*)d_in[0];
    const float* we  = (const float*)d_in[1];
    const float* wc  = (const float*)d_in[2];
    const int*   a1r = (const int*)  d_in[3];
    const int*   a1c = (const int*)  d_in[4];
    const float* a1v = (const float*)d_in[5];
    const int*   a2r = (const int*)  d_in[6];
    const int*   a2c = (const int*)  d_in[7];
    const float* a2v = (const float*)d_in[8];
    float* out = (float*)d_out;

    const int E1 = in_sizes[3];
    const int E2 = in_sizes[6];
    const int n  = in_sizes[0] / IN_C;   // 20000

    // Workspace (f16 features): r0[n*32] r1[n*64] r2[n*128], ip1/ip2, dummy
    ushort* r0 = (ushort*)d_ws;
    ushort* r1 = r0 + (size_t)n * 32;
    ushort* r2 = r1 + (size_t)n * 64;
    int*   ip1 = (int*)(r2 + (size_t)n * 128);
    int*   ip2 = ip1 + (n + 1);
    float* dummy = (float*)(ip2 + (n + 2));

    // 1) fused embed + indptr + A2 edge-list warm-touch
    {
        const int nbE = (n + 15) / 16;
        const int nbI = (n + 1 + 255) / 256;
        const int nbT = 512;
        prep_kernel<<<nbE + nbI + nbT, 256, 0, stream>>>(
            x, we, r0, a1r, E1, ip1, a2r, E2, ip2, a2c, a2v, dummy,
            n, nbE, nbI, nbT);
    }

    // 2) level 1: r1 = relu([A1 r0 | A2 r0]); C=32, ROWS=2
    //    heavy: 16 rows/block (paired), light: 8 rows/block
    {
        const int nbH = (n + 15) / 16;
        const int nbL = (n + 7) / 8;
        spmm_level<32, 2><<<nbH + nbL, 256, 0, stream>>>(
            ip1, a1c, a1v, E1, ip2, a2c, a2v, E2, r0, r1, n, nbH);
    }
    // 3) level 2: r2 = relu([A1 r1 | A2 r1]); C=64, ROWS=1
    //    heavy: 8 rows/block (paired), light: 4 rows/block
    {
        const int nbH = (n + 7) / 8;
        const int nbL = (n + 3) / 4;
        spmm_level<64, 1><<<nbH + nbL, 256, 0, stream>>>(
            ip1, a1c, a1v, E1, ip2, a2c, a2v, E2, r1, r2, n, nbH);
    }

    // 4) fused concat + classify
    classify_kernel<<<(n + 15) / 16, 256, 0, stream>>>(r0, r1, r2, wc, out, n);
}

// Round 5
// 205.385 us; speedup vs baseline: 1.1294x; 1.1294x over previous
//
#include <hip/hip_runtime.h>

typedef unsigned int uint;
typedef unsigned short ushort;

#define IN_C 128
#define HID  32

// ---- f16 helpers (fp32 accumulate everywhere; RNE on store) ---------------
__device__ __forceinline__ uint f2h2(float a, float b) {
    _Float16 ha = (_Float16)a, hb = (_Float16)b;
    unsigned short ua = __builtin_bit_cast(unsigned short, ha);
    unsigned short ub = __builtin_bit_cast(unsigned short, hb);
    return (uint)ua | ((uint)ub << 16);
}
// acc += f16_lo(pk) * v  -- single full-rate VOP3P v_fma_mix_f32, no unpack
__device__ __forceinline__ void fma_lo(float& acc, uint pk, float v) {
    asm("v_fma_mix_f32 %0, %1, %2, %0 op_sel:[0,0,0] op_sel_hi:[1,0,0]"
        : "+v"(acc) : "v"(pk), "v"(v));
}
// acc += f16_hi(pk) * v
__device__ __forceinline__ void fma_hi(float& acc, uint pk, float v) {
    asm("v_fma_mix_f32 %0, %1, %2, %0 op_sel:[1,0,0] op_sel_hi:[1,0,0]"
        : "+v"(acc) : "v"(pk), "v"(v));
}

// async global->LDS, 16 B per lane: lane i's 16B source -> ldsBase + i*16
typedef const __attribute__((address_space(1))) void* gas1_t;
typedef __attribute__((address_space(3))) void*       las3_t;
__device__ __forceinline__ void glds16(const void* g, void* l) {
    __builtin_amdgcn_global_load_lds((gas1_t)g, (las3_t)l, 16, 0, 0);
}

// ---------------------------------------------------------------------------
// K1: fused prep (unchanged).
// ---------------------------------------------------------------------------
__global__ void prep_kernel(const float* __restrict__ x,
                            const float* __restrict__ w,
                            ushort* __restrict__ r0,
                            const int* __restrict__ a1r, int E1, int* __restrict__ ip1,
                            const int* __restrict__ a2r, int E2, int* __restrict__ ip2,
                            const int* __restrict__ a2c, const float* __restrict__ a2v,
                            float* __restrict__ dummy,
                            int n, int nbE, int nbI, int nbT) {
    __shared__ float wl[IN_C * HID];
    const int tid = threadIdx.x;
    if (blockIdx.x < nbE) {
        for (int i = tid; i < IN_C * HID; i += blockDim.x) wl[i] = w[i];
        __syncthreads();
        const int row = blockIdx.x * 16 + tid / 16;
        const int h0  = (tid % 16) * 2;
        if (row >= n) return;
        const float4* xr = (const float4*)(x + (size_t)row * IN_C);
        float a0 = 0.f, a1 = 0.f;
#pragma unroll
        for (int k4 = 0; k4 < IN_C / 4; ++k4) {
            float4 xv = xr[k4];
            a0 += xv.x * wl[(4*k4+0)*HID + h0];  a1 += xv.x * wl[(4*k4+0)*HID + h0+1];
            a0 += xv.y * wl[(4*k4+1)*HID + h0];  a1 += xv.y * wl[(4*k4+1)*HID + h0+1];
            a0 += xv.z * wl[(4*k4+2)*HID + h0];  a1 += xv.z * wl[(4*k4+2)*HID + h0+1];
            a0 += xv.w * wl[(4*k4+3)*HID + h0];  a1 += xv.w * wl[(4*k4+3)*HID + h0+1];
        }
        uint p = f2h2(fmaxf(a0, 0.f), fmaxf(a1, 0.f));
        ((uint*)r0)[(size_t)row * 16 + (tid % 16)] = p;
    } else if (blockIdx.x < nbE + nbI) {
        const int i = (blockIdx.x - nbE) * 256 + tid;
        if (i > n) return;
        int lo = 0, hi = E1;
        while (lo < hi) { int m = (lo + hi) >> 1; if (a1r[m] < i) lo = m + 1; else hi = m; }
        ip1[i] = lo;
        lo = 0; hi = E2;
        while (lo < hi) { int m = (lo + hi) >> 1; if (a2r[m] < i) lo = m + 1; else hi = m; }
        ip2[i] = lo;
    } else {
        const int t = (blockIdx.x - nbE - nbI) * 256 + tid;
        const int stride = nbT * 256;
        const int total4 = E2 / 4;
        const float4* c4 = (const float4*)a2c;
        const float4* v4 = (const float4*)a2v;
        float s = 0.f;
        for (int i = t; i < total4; i += stride) {
            float4 u = c4[i], v = v4[i];
            s += u.x + u.y + u.z + u.w + v.x + v.y + v.z + v.w;
        }
        if (s == 123.456f) dummy[0] = s;   // never true in practice; defeats DCE
    }
}

// ---------------------------------------------------------------------------
// K2: fused-level SpMM + ReLU, f16 features / fp32 accumulate (v_fma_mix).
// R5: heavy (A2) path stages each row's edge list (col+val) into LDS with
// async global_load_lds (2 instructions stage 256 edges = ~1 avg row), waits
// vmcnt(0) ONCE per row, then consumes edges via ds_read_b128. This removes
// the LLC-latency edge-load from the per-iteration chain and is
// collapse-proof: the prefetch lives in LDS, so regalloc can't shrink it
// (R2/R3/R4 lesson: VGPR-resident pipelines get sunk to their uses).
// Heavy = 1 row/wave (W=64/L ways). Light (A1) path = R2 depth-1 pipeline.
// Blocks [0,nbH) = A2 (out col off C); rest = A1 (off 0).
// ---------------------------------------------------------------------------
template <int C, int ROWSL>
__global__ __launch_bounds__(256) void spmm_level(
        const int* __restrict__ ip1, const int* __restrict__ col1,
        const float* __restrict__ val1, int E1,
        const int* __restrict__ ip2, const int* __restrict__ col2,
        const float* __restrict__ val2, int E2,
        const ushort* __restrict__ xin, ushort* __restrict__ out,
        int n, int nbH) {
    constexpr int L = C / 8;                 // feature lanes per row (4 or 8)
    __shared__ __align__(16) int   scol[4][256];
    __shared__ __align__(16) float sval[4][256];

    const int lane = threadIdx.x & 63;
    const int wave = threadIdx.x >> 6;
    (void)E1;

    int bid = blockIdx.x;
    if (bid < nbH) {
        // ---------------- heavy path: A2, one row per wave -----------------
        constexpr int W = 64 / L;            // edge ways (16 for C=32, 8 for C=64)
        const int fl  = lane % L;
        const int way = lane / L;
        const uint flo = (uint)fl * 16u;

        auto gat = [&](uint c) -> uint4 {
            return *(const uint4*)((const char*)xin + (c * (uint)(2 * C) + flo));
        };
        float acc[8];
#pragma unroll
        for (int j = 0; j < 8; ++j) acc[j] = 0.f;
        auto fmadd = [&](const uint4& u, float v) {
            fma_lo(acc[0], u.x, v); fma_hi(acc[1], u.x, v);
            fma_lo(acc[2], u.y, v); fma_hi(acc[3], u.y, v);
            fma_lo(acc[4], u.z, v); fma_hi(acc[5], u.z, v);
            fma_lo(acc[6], u.w, v); fma_hi(acc[7], u.w, v);
        };

        const int row = bid * 4 + wave;
        if (row >= n) return;
        const int s = ip2[row];
        const int e = ip2[row + 1];

        // unaligned head (<=3 edges), straight from global
        int sv = (s + 3) & ~3; if (sv > e) sv = e;
        for (int idx = s + way; idx < sv; idx += W)
            fmadd(gat((uint)col2[idx]), val2[idx]);

        const int lastA = (E2 - 4) & ~3;     // last aligned 4-int chunk start
        int*   myc = &scol[wave][0];
        float* myv = &sval[wave][0];

        for (int base = sv; base < e; base += 256) {
            const int cnt = (e - base < 256) ? (e - base) : 256;
            // async stage this chunk's col+val (lane i -> lds + i*16)
            int so = base + lane * 4; if (so > lastA) so = lastA;
            glds16(col2 + so, myc);
            glds16(val2 + so, myv);
            asm volatile("s_waitcnt vmcnt(0)" ::: "memory");
            __builtin_amdgcn_sched_barrier(0);
            // consume: 4-edge batches per way from LDS
            const int nb = cnt / (4 * W);
            for (int b = 0; b < nb; ++b) {
                const int o = (b * W + way) * 4;
                const int4   cc = *(const int4*)  (myc + o);
                const float4 vv = *(const float4*)(myv + o);
                const uint4 g0 = gat((uint)cc.x), g1 = gat((uint)cc.y),
                            g2 = gat((uint)cc.z), g3 = gat((uint)cc.w);
                fmadd(g0, vv.x); fmadd(g1, vv.y);
                fmadd(g2, vv.z); fmadd(g3, vv.w);
            }
            // per-edge tail within the chunk
            for (int k = nb * 4 * W + way; k < cnt; k += W)
                fmadd(gat((uint)myc[k]), myv[k]);
        }

        // cross-way reduction (ways share a full wave here)
#pragma unroll
        for (int m = L; m < 64; m <<= 1)
#pragma unroll
            for (int j = 0; j < 8; ++j) acc[j] += __shfl_xor(acc[j], m, 64);

        if (way == 0) {
            uint4 p;
            p.x = f2h2(fmaxf(acc[0], 0.f), fmaxf(acc[1], 0.f));
            p.y = f2h2(fmaxf(acc[2], 0.f), fmaxf(acc[3], 0.f));
            p.z = f2h2(fmaxf(acc[4], 0.f), fmaxf(acc[5], 0.f));
            p.w = f2h2(fmaxf(acc[6], 0.f), fmaxf(acc[7], 0.f));
            *(uint4*)(out + (size_t)row * (2 * C) + C + fl * 8) = p;
        }
    } else {
        // ---------------- light path: A1 (R2 structure) --------------------
        bid -= nbH;
        constexpr int SUBL = 64 / ROWSL;
        constexpr int WL   = SUBL / L;
        const int sub = lane / SUBL;
        const int li  = lane % SUBL;
        const int fl  = li % L;
        const int way = li / L;
        const uint flo = (uint)fl * 16u;

        auto gat = [&](uint c) -> uint4 {
            return *(const uint4*)((const char*)xin + (c * (uint)(2 * C) + flo));
        };
        float acc[8];
#pragma unroll
        for (int j = 0; j < 8; ++j) acc[j] = 0.f;
        auto fmadd = [&](const uint4& u, float v) {
            fma_lo(acc[0], u.x, v); fma_hi(acc[1], u.x, v);
            fma_lo(acc[2], u.y, v); fma_hi(acc[3], u.y, v);
            fma_lo(acc[4], u.z, v); fma_hi(acc[5], u.z, v);
            fma_lo(acc[6], u.w, v); fma_hi(acc[7], u.w, v);
        };

        const int row = (bid * 4 + wave) * ROWSL + sub;
        if (row >= n) return;
        const int s = ip1[row];
        const int e = ip1[row + 1];
        int idx0 = s + way;
        if (idx0 < e) {
            int c0 = col1[idx0]; float v0 = val1[idx0];
            int idx1 = idx0 + WL;
            int c1 = 0; float v1 = 0.f;
            if (idx1 < e) { c1 = col1[idx1]; v1 = val1[idx1]; }
            uint4 g0 = gat((uint)c0);
            while (true) {
                int idx2 = idx1 + WL;
                int c2 = 0; float v2 = 0.f;
                if (idx2 < e) { c2 = col1[idx2]; v2 = val1[idx2]; }
                uint4 g1 = gat((uint)c1);
                fmadd(g0, v0);
                if (idx1 >= e) break;
                g0 = g1; c1 = c2; v0 = v1; v1 = v2;
                idx1 = idx2;
            }
        }
#pragma unroll
        for (int m = L; m < SUBL; m <<= 1)
#pragma unroll
            for (int j = 0; j < 8; ++j) acc[j] += __shfl_xor(acc[j], m, 64);
        if (way == 0) {
            uint4 p;
            p.x = f2h2(fmaxf(acc[0], 0.f), fmaxf(acc[1], 0.f));
            p.y = f2h2(fmaxf(acc[2], 0.f), fmaxf(acc[3], 0.f));
            p.z = f2h2(fmaxf(acc[4], 0.f), fmaxf(acc[5], 0.f));
            p.w = f2h2(fmaxf(acc[6], 0.f), fmaxf(acc[7], 0.f));
            *(uint4*)(out + (size_t)row * (2 * C) + fl * 8) = p;
        }
    }
}

// ---------------------------------------------------------------------------
// K3: out = [r0 | r1 | r2] @ w_classify  (f16 features via v_fma_mix,
// fp32 weights in LDS)
// ---------------------------------------------------------------------------
#define CDIM 224
#define OUT_C 16
__global__ void classify_kernel(const ushort* __restrict__ r0,
                                const ushort* __restrict__ r1,
                                const ushort* __restrict__ r2,
                                const float* __restrict__ w,
                                float* __restrict__ out, int n) {
    __shared__ float wl[CDIM * OUT_C];
    const int tid = threadIdx.x;
    for (int i = tid; i < CDIM * OUT_C; i += blockDim.x) wl[i] = w[i];
    __syncthreads();
    const int row = blockIdx.x * 16 + tid / 16;
    const int o   = tid % 16;
    if (row >= n) return;
    float acc = 0.f;

    const uint4* a = (const uint4*)(r0 + (size_t)row * 32);
#pragma unroll
    for (int q = 0; q < 4; ++q) {
        uint4 u = a[q]; int j = q * 8;
        fma_lo(acc, u.x, wl[(j+0)*OUT_C + o]);  fma_hi(acc, u.x, wl[(j+1)*OUT_C + o]);
        fma_lo(acc, u.y, wl[(j+2)*OUT_C + o]);  fma_hi(acc, u.y, wl[(j+3)*OUT_C + o]);
        fma_lo(acc, u.z, wl[(j+4)*OUT_C + o]);  fma_hi(acc, u.z, wl[(j+5)*OUT_C + o]);
        fma_lo(acc, u.w, wl[(j+6)*OUT_C + o]);  fma_hi(acc, u.w, wl[(j+7)*OUT_C + o]);
    }
    const uint4* b = (const uint4*)(r1 + (size_t)row * 64);
#pragma unroll
    for (int q = 0; q < 8; ++q) {
        uint4 u = b[q]; int j = 32 + q * 8;
        fma_lo(acc, u.x, wl[(j+0)*OUT_C + o]);  fma_hi(acc, u.x, wl[(j+1)*OUT_C + o]);
        fma_lo(acc, u.y, wl[(j+2)*OUT_C + o]);  fma_hi(acc, u.y, wl[(j+3)*OUT_C + o]);
        fma_lo(acc, u.z, wl[(j+4)*OUT_C + o]);  fma_hi(acc, u.z, wl[(j+5)*OUT_C + o]);
        fma_lo(acc, u.w, wl[(j+6)*OUT_C + o]);  fma_hi(acc, u.w, wl[(j+7)*OUT_C + o]);
    }
    const uint4* c = (const uint4*)(r2 + (size_t)row * 128);
#pragma unroll
    for (int q = 0; q < 16; ++q) {
        uint4 u = c[q]; int j = 96 + q * 8;
        fma_lo(acc, u.x, wl[(j+0)*OUT_C + o]);  fma_hi(acc, u.x, wl[(j+1)*OUT_C + o]);
        fma_lo(acc, u.y, wl[(j+2)*OUT_C + o]);  fma_hi(acc, u.y, wl[(j+3)*OUT_C + o]);
        fma_lo(acc, u.z, wl[(j+4)*OUT_C + o]);  fma_hi(acc, u.z, wl[(j+5)*OUT_C + o]);
        fma_lo(acc, u.w, wl[(j+6)*OUT_C + o]);  fma_hi(acc, u.w, wl[(j+7)*OUT_C + o]);
    }
    out[(size_t)row * OUT_C + o] = acc;
}

// ---------------------------------------------------------------------------
extern "C" void kernel_launch(void* const* d_in, const int* in_sizes, int n_in,
                              void* d_out, int out_size, void* d_ws, size_t ws_size,
                              hipStream_t stream) {
    const float* x   = (const float*)d_in[0];
    const float* we  = (const float*)d_in[1];
    const float* wc  = (const float*)d_in[2];
    const int*   a1r = (const int*)  d_in[3];
    const int*   a1c = (const int*)  d_in[4];
    const float* a1v = (const float*)d_in[5];
    const int*   a2r = (const int*)  d_in[6];
    const int*   a2c = (const int*)  d_in[7];
    const float* a2v = (const float*)d_in[8];
    float* out = (float*)d_out;

    const int E1 = in_sizes[3];
    const int E2 = in_sizes[6];
    const int n  = in_sizes[0] / IN_C;   // 20000

    // Workspace (f16 features): r0[n*32] r1[n*64] r2[n*128], ip1/ip2, dummy
    ushort* r0 = (ushort*)d_ws;
    ushort* r1 = r0 + (size_t)n * 32;
    ushort* r2 = r1 + (size_t)n * 64;
    int*   ip1 = (int*)(r2 + (size_t)n * 128);
    int*   ip2 = ip1 + (n + 1);
    float* dummy = (float*)(ip2 + (n + 2));

    // 1) fused embed + indptr + A2 edge-list warm-touch
    {
        const int nbE = (n + 15) / 16;
        const int nbI = (n + 1 + 255) / 256;
        const int nbT = 512;
        prep_kernel<<<nbE + nbI + nbT, 256, 0, stream>>>(
            x, we, r0, a1r, E1, ip1, a2r, E2, ip2, a2c, a2v, dummy,
            n, nbE, nbI, nbT);
    }

    // 2) level 1: r1 = relu([A1 r0 | A2 r0]); C=32
    //    heavy: 1 row/wave (4 rows/block); light: ROWSL=2 (8 rows/block)
    {
        const int nbH = (n + 3) / 4;
        const int nbL = (n + 7) / 8;
        spmm_level<32, 2><<<nbH + nbL, 256, 0, stream>>>(
            ip1, a1c, a1v, E1, ip2, a2c, a2v, E2, r0, r1, n, nbH);
    }
    // 3) level 2: r2 = relu([A1 r1 | A2 r1]); C=64
    //    heavy: 1 row/wave (4 rows/block); light: ROWSL=1 (4 rows/block)
    {
        const int nbH = (n + 3) / 4;
        const int nbL = (n + 3) / 4;
        spmm_level<64, 1><<<nbH + nbL, 256, 0, stream>>>(
            ip1, a1c, a1v, E1, ip2, a2c, a2v, E2, r1, r2, n, nbH);
    }

    // 4) fused concat + classify
    classify_kernel<<<(n + 15) / 16, 256, 0, stream>>>(r0, r1, r2, wc, out, n);
}